// Round 4
// baseline (140.149 us; speedup 1.0000x reference)
//
#include <hip/hip_runtime.h>
#include <hip/hip_bf16.h>
#include <stdint.h>

typedef int v4i __attribute__((ext_vector_type(4)));

#define GPTR(p) ((const __attribute__((address_space(1))) void*)(p))
#define LPTR(p) ((__attribute__((address_space(3))) void*)(p))

__device__ __forceinline__ float wave_max(float m) {
#pragma unroll
  for (int off = 32; off > 0; off >>= 1)
    m = fmaxf(m, __shfl_xor(m, off, 64));
  return m;
}

// branch-free erf (Abramowitz-Stegun 7.1.26), |err| <= 1.5e-7 absolute
__device__ __forceinline__ float fast_erf(float x) {
  const float ax = fabsf(x);
  const float t = __builtin_amdgcn_rcpf(fmaf(0.3275911f, ax, 1.0f));
  float p = fmaf(1.061405429f, t, -1.453152027f);
  p = fmaf(p, t, 1.421413741f);
  p = fmaf(p, t, -0.284496736f);
  p = fmaf(p, t, 0.254829592f);
  const float e = __expf(-ax * ax);
  const float r = 1.0f - p * t * e;
  return copysignf(r, x);
}

__device__ __forceinline__ float gelu_exact(float f) {
  return 0.5f * f * (1.0f + fast_erf(f * 0.70710678118654752f));
}

// fused absmax of {x*smul, w1, w2} -> scal[0..2], one atomic per block
__global__ void absmax3_kernel(const float* __restrict__ x, int nx4,
                               const float* __restrict__ smul,
                               const float* __restrict__ w1, int nw14,
                               const float* __restrict__ w2, int nw24,
                               unsigned* __restrict__ scal) {
  __shared__ float red[4];
  const int bid = blockIdx.x;
  const float4* s4;
  int n4, b0, nb;
  float s = 1.0f;
  unsigned* dst;
  if (bid < 512)      { s4 = (const float4*)x;  n4 = nx4;  s = smul[0]; dst = scal;     b0 = bid;       nb = 512; }
  else if (bid < 640) { s4 = (const float4*)w1; n4 = nw14;              dst = scal + 1; b0 = bid - 512; nb = 128; }
  else                { s4 = (const float4*)w2; n4 = nw24;              dst = scal + 2; b0 = bid - 640; nb = 128; }
  float m = 0.0f;
  const int stride = nb * blockDim.x;
  for (int i = b0 * blockDim.x + threadIdx.x; i < n4; i += stride) {
    float4 v = s4[i];
    m = fmaxf(m, fabsf(v.x * s));
    m = fmaxf(m, fabsf(v.y * s));
    m = fmaxf(m, fabsf(v.z * s));
    m = fmaxf(m, fabsf(v.w * s));
  }
  m = wave_max(m);
  if ((threadIdx.x & 63) == 0) red[threadIdx.x >> 6] = m;
  __syncthreads();
  if (threadIdx.x == 0)
    atomicMax(dst, __float_as_uint(fmaxf(fmaxf(red[0], red[1]), fmaxf(red[2], red[3]))));
}

// fused quantize of {x*smul, w1, w2} -> qx, qw1, qw2
__global__ void quantize3_kernel(const float* __restrict__ x, int nx4,
                                 const float* __restrict__ smul,
                                 const float* __restrict__ w1, int nw14,
                                 const float* __restrict__ w2, int nw24,
                                 const unsigned* __restrict__ scal,
                                 int8_t* __restrict__ qx,
                                 int8_t* __restrict__ qw1,
                                 int8_t* __restrict__ qw2) {
  const int bid = blockIdx.x;
  const float4* s4;
  char4* d4;
  int n4, b0, nb;
  float s = 1.0f, mx;
  if (bid < 2048)      { s4 = (const float4*)x;  d4 = (char4*)qx;  n4 = nx4;  s = smul[0]; mx = __uint_as_float(scal[0]); b0 = bid;        nb = 2048; }
  else if (bid < 2176) { s4 = (const float4*)w1; d4 = (char4*)qw1; n4 = nw14;              mx = __uint_as_float(scal[1]); b0 = bid - 2048; nb = 128; }
  else                 { s4 = (const float4*)w2; d4 = (char4*)qw2; n4 = nw24;              mx = __uint_as_float(scal[2]); b0 = bid - 2176; nb = 128; }
  const float scale = mx / 127.0f;  // exact IEEE divide, matches reference
  const int stride = nb * blockDim.x;
  for (int i = b0 * blockDim.x + threadIdx.x; i < n4; i += stride) {
    float4 v = s4[i];
    char4 qq;
    qq.x = (signed char)(int)rintf(fminf(fmaxf((v.x * s) / scale, -128.0f), 127.0f));
    qq.y = (signed char)(int)rintf(fminf(fmaxf((v.y * s) / scale, -128.0f), 127.0f));
    qq.z = (signed char)(int)rintf(fminf(fmaxf((v.z * s) / scale, -128.0f), 127.0f));
    qq.w = (signed char)(int)rintf(fminf(fmaxf((v.w * s) / scale, -128.0f), 127.0f));
    d4[i] = qq;
  }
}

// reduce partial maxima of raw fc1 output f; s_h numerator = max|gelu|:
// gelu increasing for f>0; |gelu| <= max(gelu(max_f), 0.1699702) (global min |gelu|).
__global__ void reduce_scale_kernel(const float* __restrict__ partial, int n,
                                    unsigned* __restrict__ scal) {
  __shared__ float red[4];
  float m = -3.4e38f;
  for (int i = threadIdx.x; i < n; i += blockDim.x) m = fmaxf(m, partial[i]);
  m = wave_max(m);
  if ((threadIdx.x & 63) == 0) red[threadIdx.x >> 6] = m;
  __syncthreads();
  if (threadIdx.x == 0) {
    m = fmaxf(fmaxf(red[0], red[1]), fmaxf(red[2], red[3]));
    const float sx = __uint_as_float(scal[0]) / 127.0f;
    const float sw = __uint_as_float(scal[1]) / 127.0f;
    const float max_f = m * (sw * sx);  // same fp ops as per-element path
    scal[3] = __float_as_uint(fmaxf(gelu_exact(max_f), 0.1699702f));
  }
}

// C = A[M,K] @ B[N,K]^T, int8 -> int32 MFMA. BM=BN=128, BK=64, 2x2 waves.
// Swapped-operand MFMA (bf first) -> C^T fragments: lane holds 4 consecutive
// n (cols) for fixed m (row) => direct char4/float4 stores, no LDS repack.
// 3-buffer pipeline, counted vmcnt (never 0 in main loop), raw s_barrier.
// EPI 0: per-block max of f = acc + bias -> partial[]
// EPI 1: store qh = rint(clip(gelu(f*s1)/s_h)) int8 (char4)
// EPI 2: store out = (acc+b2)*s2 f32 (float4)
template <int EPI>
__global__ __launch_bounds__(256, 3)
void gemm_i8_kernel(const int8_t* __restrict__ A, const int8_t* __restrict__ B,
                    const float* __restrict__ bias,
                    const unsigned* __restrict__ scal,
                    float* __restrict__ partial,
                    int8_t* __restrict__ out_i8,
                    float* __restrict__ out_f32,
                    int N, int K, int GN) {
  __shared__ __align__(16) int8_t lA[3][128 * 64];
  __shared__ __align__(16) int8_t lB[3][128 * 64];
  __shared__ float red[4];

  // bijective XCD swizzle (m204): contiguous work chunk per XCD
  const int nwg = gridDim.x;
  const int q = nwg >> 3, rr = nwg & 7;
  const int xcd = blockIdx.x & 7, sub = blockIdx.x >> 3;
  const int wg = (xcd < rr ? xcd * (q + 1) : rr * (q + 1) + (xcd - rr) * q) + sub;
  const int bx = wg % GN;   // n-tile (fastest: shares A panel)
  const int by = wg / GN;   // m-tile

  const int t = threadIdx.x;
  const int lane = t & 63;
  const int wave = t >> 6;
  const int wr = wave >> 1;
  const int wc = wave & 1;
  const size_t m0 = (size_t)by * 128;
  const int n0 = bx * 128;

  const int8_t* Ab = A + m0 * (size_t)K;
  const int8_t* Bb = B + (size_t)n0 * (size_t)K;

  v4i acc[4][4] = {};
  const int KT = K >> 6;  // BK = 64; KT >= 3 always here (6 or 24)

  // Staging: linear LDS fill; XOR slot-swizzle f(row)=(row>>1)&3 pre-applied
  // on the GLOBAL source address (both-sides rule). 64B rows = 4 x 16B slots.
  const int row0 = t >> 2;
  const int ss = (t & 3) ^ ((row0 >> 1) & 3);
  const int ubase = __builtin_amdgcn_readfirstlane((t & 192) * 16);
  const size_t srcA0 = (size_t)row0 * K + (size_t)(ss * 16);
  const size_t srcA1 = (size_t)(row0 + 64) * K + (size_t)(ss * 16);

  auto stage = [&](int buf, int kt) {
    const int8_t* ga = Ab + kt * 64;
    const int8_t* gb = Bb + kt * 64;
    __builtin_amdgcn_global_load_lds(GPTR(ga + srcA0), LPTR(&lA[buf][ubase]), 16, 0, 0);
    __builtin_amdgcn_global_load_lds(GPTR(ga + srcA1), LPTR(&lA[buf][4096 + ubase]), 16, 0, 0);
    __builtin_amdgcn_global_load_lds(GPTR(gb + srcA0), LPTR(&lB[buf][ubase]), 16, 0, 0);
    __builtin_amdgcn_global_load_lds(GPTR(gb + srcA1), LPTR(&lB[buf][4096 + ubase]), 16, 0, 0);
  };

  const int r15 = lane & 15;
  const int q4 = lane >> 4;

  auto compute = [&](int buf) {
    v4i af[4], bf[4];
#pragma unroll
    for (int fr = 0; fr < 4; ++fr) {
      const int row = wr * 64 + fr * 16 + r15;
      const int slot = q4 ^ ((row >> 1) & 3);
      af[fr] = *(const v4i*)(&lA[buf][row * 64 + slot * 16]);
    }
#pragma unroll
    for (int fc = 0; fc < 4; ++fc) {
      const int row = wc * 64 + fc * 16 + r15;
      const int slot = q4 ^ ((row >> 1) & 3);
      bf[fc] = *(const v4i*)(&lB[buf][row * 64 + slot * 16]);
    }
    // swapped operands: D = C^T. row(lane>>4*4+reg) = n, col(lane&15) = m.
#pragma unroll
    for (int fr = 0; fr < 4; ++fr)
#pragma unroll
      for (int fc = 0; fc < 4; ++fc)
        acc[fr][fc] = __builtin_amdgcn_mfma_i32_16x16x64_i8(bf[fc], af[fr], acc[fr][fc], 0, 0, 0);
  };

#define CBAR()                          \
  do {                                  \
    __builtin_amdgcn_sched_barrier(0);  \
    __builtin_amdgcn_s_barrier();       \
    __builtin_amdgcn_sched_barrier(0);  \
  } while (0)

  stage(0, 0);
  stage(1, 1);
  stage(2, 2);
  int cur = 0;
  for (int kt = 0; kt <= KT - 3; ++kt) {
    asm volatile("s_waitcnt vmcnt(8)" ::: "memory");  // stage kt landed (mine)
    CBAR();                                           // everyone's landed
    compute(cur);
    asm volatile("s_waitcnt lgkmcnt(0)" ::: "memory");  // my ds_reads of cur done
    CBAR();                                             // all waves done with cur
    if (kt + 3 < KT) stage(cur, kt + 3);
    cur = (cur == 2) ? 0 : cur + 1;
  }
  // kt = KT-2
  asm volatile("s_waitcnt vmcnt(4)" ::: "memory");
  CBAR();
  compute(cur);
  cur = (cur == 2) ? 0 : cur + 1;
  // kt = KT-1
  asm volatile("s_waitcnt vmcnt(0)" ::: "memory");
  CBAR();
  compute(cur);
#undef CBAR

  // Epilogue (C^T fragments): m = m0+wr*64+fr*16+r15 ; n = n0+wc*64+fc*16+q4*4+r
  if constexpr (EPI == 0) {
    float lm = -3.4e38f;
#pragma unroll
    for (int fc = 0; fc < 4; ++fc) {
      const float4 bv4 = *(const float4*)&bias[n0 + wc * 64 + fc * 16 + q4 * 4];
#pragma unroll
      for (int fr = 0; fr < 4; ++fr) {
        lm = fmaxf(lm, (float)acc[fr][fc][0] + bv4.x);
        lm = fmaxf(lm, (float)acc[fr][fc][1] + bv4.y);
        lm = fmaxf(lm, (float)acc[fr][fc][2] + bv4.z);
        lm = fmaxf(lm, (float)acc[fr][fc][3] + bv4.w);
      }
    }
    lm = wave_max(lm);
    if (lane == 0) red[wave] = lm;
    __syncthreads();
    if (t == 0)
      partial[wg] = fmaxf(fmaxf(red[0], red[1]), fmaxf(red[2], red[3]));
  } else if constexpr (EPI == 1) {
    const float sx = __uint_as_float(scal[0]) / 127.0f;
    const float sw = __uint_as_float(scal[1]) / 127.0f;
    const float s1 = sw * sx;
    const float sh = __uint_as_float(scal[3]) / 127.0f;
    const float inv_sh = __builtin_amdgcn_rcpf(sh);
#pragma unroll
    for (int fc = 0; fc < 4; ++fc) {
      const int nb = n0 + wc * 64 + fc * 16 + q4 * 4;
      const float4 bv4 = *(const float4*)&bias[nb];
#pragma unroll
      for (int fr = 0; fr < 4; ++fr) {
        const size_t m = m0 + (size_t)(wr * 64 + fr * 16 + r15);
        char4 qq;
        {
          const float f = ((float)acc[fr][fc][0] + bv4.x) * s1;
          qq.x = (signed char)(int)rintf(fminf(fmaxf(gelu_exact(f) * inv_sh, -128.0f), 127.0f));
        }
        {
          const float f = ((float)acc[fr][fc][1] + bv4.y) * s1;
          qq.y = (signed char)(int)rintf(fminf(fmaxf(gelu_exact(f) * inv_sh, -128.0f), 127.0f));
        }
        {
          const float f = ((float)acc[fr][fc][2] + bv4.z) * s1;
          qq.z = (signed char)(int)rintf(fminf(fmaxf(gelu_exact(f) * inv_sh, -128.0f), 127.0f));
        }
        {
          const float f = ((float)acc[fr][fc][3] + bv4.w) * s1;
          qq.w = (signed char)(int)rintf(fminf(fmaxf(gelu_exact(f) * inv_sh, -128.0f), 127.0f));
        }
        *(char4*)(out_i8 + m * (size_t)N + nb) = qq;
      }
    }
  } else {
    const float sw2 = __uint_as_float(scal[2]) / 127.0f;
    const float sh = __uint_as_float(scal[3]) / 127.0f;
    const float x2max = 127.0f * sh;
    const float sx2 = x2max / 127.0f;
    const float s2 = sw2 * sx2;
#pragma unroll
    for (int fc = 0; fc < 4; ++fc) {
      const int nb = n0 + wc * 64 + fc * 16 + q4 * 4;
      const float4 bv4 = *(const float4*)&bias[nb];
#pragma unroll
      for (int fr = 0; fr < 4; ++fr) {
        const size_t m = m0 + (size_t)(wr * 64 + fr * 16 + r15);
        float4 o;
        o.x = ((float)acc[fr][fc][0] + bv4.x) * s2;
        o.y = ((float)acc[fr][fc][1] + bv4.y) * s2;
        o.z = ((float)acc[fr][fc][2] + bv4.z) * s2;
        o.w = ((float)acc[fr][fc][3] + bv4.w) * s2;
        *(float4*)(out_f32 + m * (size_t)N + nb) = o;
      }
    }
  }
}

extern "C" void kernel_launch(void* const* d_in, const int* in_sizes, int n_in,
                              void* d_out, int out_size, void* d_ws, size_t ws_size,
                              hipStream_t stream) {
  const float* x   = (const float*)d_in[0];
  const float* sxp = (const float*)d_in[1];
  const float* w1  = (const float*)d_in[2];
  const float* b1  = (const float*)d_in[3];
  const float* w2  = (const float*)d_in[4];
  const float* b2  = (const float*)d_in[5];

  const int H = in_sizes[3];      // 1536
  const int D = in_sizes[5];      // 384
  const int M = in_sizes[0] / D;  // 25216 = 197*128
  const int GM = M / 128;         // 197
  const int GN1 = H / 128;        // 12
  const int GN2 = D / 128;        // 3

  uint8_t* ws = (uint8_t*)d_ws;
  unsigned* scal = (unsigned*)ws;  // [0]=max|x2| [1]=max|w1| [2]=max|w2| [3]=max|g|
  size_t off = 256;
  float* partial = (float*)(ws + off); off += 16384;
  int8_t* qx  = (int8_t*)(ws + off); off += (size_t)M * D;
  int8_t* qw1 = (int8_t*)(ws + off); off += (size_t)H * D;
  int8_t* qw2 = (int8_t*)(ws + off); off += (size_t)D * H;
  int8_t* qh  = (int8_t*)(ws + off); off += (size_t)M * H;
  (void)ws_size; (void)n_in; (void)out_size;

  hipMemsetAsync(scal, 0, 16, stream);

  absmax3_kernel<<<dim3(768), dim3(256), 0, stream>>>(
      x, M * D / 4, sxp, w1, H * D / 4, w2, D * H / 4, scal);

  quantize3_kernel<<<dim3(2304), dim3(256), 0, stream>>>(
      x, M * D / 4, sxp, w1, H * D / 4, w2, D * H / 4, scal, qx, qw1, qw2);

  dim3 blk(256);
  dim3 g1(GN1 * GM);  // 1D grid, swizzled in-kernel
  gemm_i8_kernel<0><<<g1, blk, 0, stream>>>(qx, qw1, b1, scal, partial, nullptr, nullptr, H, D, GN1);
  reduce_scale_kernel<<<1, 256, 0, stream>>>(partial, GM * GN1, scal);
  gemm_i8_kernel<1><<<g1, blk, 0, stream>>>(qx, qw1, b1, scal, nullptr, qh, nullptr, H, D, GN1);

  dim3 g2(GN2 * GM);  // 591
  gemm_i8_kernel<2><<<g2, blk, 0, stream>>>(qh, qw2, b2, scal, nullptr, nullptr, (float*)d_out, D, H, GN2);
}

// Round 5
// 131.735 us; speedup vs baseline: 1.0639x; 1.0639x over previous
//
#include <hip/hip_runtime.h>
#include <hip/hip_bf16.h>
#include <stdint.h>

typedef int v4i __attribute__((ext_vector_type(4)));

#define GPTR(p) ((const __attribute__((address_space(1))) void*)(p))
#define LPTR(p) ((__attribute__((address_space(3))) void*)(p))

__device__ __forceinline__ float wave_max(float m) {
#pragma unroll
  for (int off = 32; off > 0; off >>= 1)
    m = fmaxf(m, __shfl_xor(m, off, 64));
  return m;
}

// branch-free erf (Abramowitz-Stegun 7.1.26), |err| <= 1.5e-7 absolute
__device__ __forceinline__ float fast_erf(float x) {
  const float ax = fabsf(x);
  const float t = __builtin_amdgcn_rcpf(fmaf(0.3275911f, ax, 1.0f));
  float p = fmaf(1.061405429f, t, -1.453152027f);
  p = fmaf(p, t, 1.421413741f);
  p = fmaf(p, t, -0.284496736f);
  p = fmaf(p, t, 0.254829592f);
  const float e = __expf(-ax * ax);
  const float r = 1.0f - p * t * e;
  return copysignf(r, x);
}

__device__ __forceinline__ float gelu_exact(float f) {
  return 0.5f * f * (1.0f + fast_erf(f * 0.70710678118654752f));
}

// fused absmax of {x*smul, w1, w2} -> scal[0..2], one atomic per block
__global__ void absmax3_kernel(const float* __restrict__ x, int nx4,
                               const float* __restrict__ smul,
                               const float* __restrict__ w1, int nw14,
                               const float* __restrict__ w2, int nw24,
                               unsigned* __restrict__ scal) {
  __shared__ float red[4];
  const int bid = blockIdx.x;
  const float4* s4;
  int n4, b0, nb;
  float s = 1.0f;
  unsigned* dst;
  if (bid < 512)      { s4 = (const float4*)x;  n4 = nx4;  s = smul[0]; dst = scal;     b0 = bid;       nb = 512; }
  else if (bid < 640) { s4 = (const float4*)w1; n4 = nw14;              dst = scal + 1; b0 = bid - 512; nb = 128; }
  else                { s4 = (const float4*)w2; n4 = nw24;              dst = scal + 2; b0 = bid - 640; nb = 128; }
  float m = 0.0f;
  const int stride = nb * blockDim.x;
  for (int i = b0 * blockDim.x + threadIdx.x; i < n4; i += stride) {
    float4 v = s4[i];
    m = fmaxf(m, fabsf(v.x * s));
    m = fmaxf(m, fabsf(v.y * s));
    m = fmaxf(m, fabsf(v.z * s));
    m = fmaxf(m, fabsf(v.w * s));
  }
  m = wave_max(m);
  if ((threadIdx.x & 63) == 0) red[threadIdx.x >> 6] = m;
  __syncthreads();
  if (threadIdx.x == 0)
    atomicMax(dst, __float_as_uint(fmaxf(fmaxf(red[0], red[1]), fmaxf(red[2], red[3]))));
}

// fused quantize of {x*smul, w1, w2} -> qx, qw1, qw2
__global__ void quantize3_kernel(const float* __restrict__ x, int nx4,
                                 const float* __restrict__ smul,
                                 const float* __restrict__ w1, int nw14,
                                 const float* __restrict__ w2, int nw24,
                                 const unsigned* __restrict__ scal,
                                 int8_t* __restrict__ qx,
                                 int8_t* __restrict__ qw1,
                                 int8_t* __restrict__ qw2) {
  const int bid = blockIdx.x;
  const float4* s4;
  char4* d4;
  int n4, b0, nb;
  float s = 1.0f, mx;
  if (bid < 2048)      { s4 = (const float4*)x;  d4 = (char4*)qx;  n4 = nx4;  s = smul[0]; mx = __uint_as_float(scal[0]); b0 = bid;        nb = 2048; }
  else if (bid < 2176) { s4 = (const float4*)w1; d4 = (char4*)qw1; n4 = nw14;              mx = __uint_as_float(scal[1]); b0 = bid - 2048; nb = 128; }
  else                 { s4 = (const float4*)w2; d4 = (char4*)qw2; n4 = nw24;              mx = __uint_as_float(scal[2]); b0 = bid - 2176; nb = 128; }
  const float scale = mx / 127.0f;  // exact IEEE divide, matches reference
  const int stride = nb * blockDim.x;
  for (int i = b0 * blockDim.x + threadIdx.x; i < n4; i += stride) {
    float4 v = s4[i];
    char4 qq;
    qq.x = (signed char)(int)rintf(fminf(fmaxf((v.x * s) / scale, -128.0f), 127.0f));
    qq.y = (signed char)(int)rintf(fminf(fmaxf((v.y * s) / scale, -128.0f), 127.0f));
    qq.z = (signed char)(int)rintf(fminf(fmaxf((v.z * s) / scale, -128.0f), 127.0f));
    qq.w = (signed char)(int)rintf(fminf(fmaxf((v.w * s) / scale, -128.0f), 127.0f));
    d4[i] = qq;
  }
}

// reduce partial maxima of raw fc1 output f; s_h numerator = max|gelu|:
// gelu increasing for f>0; |gelu| <= max(gelu(max_f), 0.1699702) (global min |gelu|).
__global__ void reduce_scale_kernel(const float* __restrict__ partial, int n,
                                    unsigned* __restrict__ scal) {
  __shared__ float red[4];
  float m = -3.4e38f;
  for (int i = threadIdx.x; i < n; i += blockDim.x) m = fmaxf(m, partial[i]);
  m = wave_max(m);
  if ((threadIdx.x & 63) == 0) red[threadIdx.x >> 6] = m;
  __syncthreads();
  if (threadIdx.x == 0) {
    m = fmaxf(fmaxf(red[0], red[1]), fmaxf(red[2], red[3]));
    const float sx = __uint_as_float(scal[0]) / 127.0f;
    const float sw = __uint_as_float(scal[1]) / 127.0f;
    const float max_f = m * (sw * sx);  // same fp ops as per-element path
    scal[3] = __float_as_uint(fmaxf(gelu_exact(max_f), 0.1699702f));
  }
}

// C = A[M,K] @ B[N,K]^T, int8 -> int32 MFMA. BM=BN=128, BK=64, 2x2 waves.
// Unswapped MFMA: C[row=m][col=n], m = (lane>>4)*4+reg, n = lane&15 -> per
// store instr lanes cover 4 rows x 16 consecutive elems (coalesced-ish).
// Simple 2-buffer loop, one __syncthreads per K-step (r3 structure).
// EPI 0: per-block max of (max_m acc) + bias -> partial[] (int max epilogue)
// EPI 1: store qh = rint(clip(gelu(f*s1)/s_h)) int8, direct byte stores
// EPI 2: store out = (acc+b2)*s2 f32, direct dword stores
template <int EPI>
__global__ __launch_bounds__(256, 4)
void gemm_i8_kernel(const int8_t* __restrict__ A, const int8_t* __restrict__ B,
                    const float* __restrict__ bias,
                    const unsigned* __restrict__ scal,
                    float* __restrict__ partial,
                    int8_t* __restrict__ out_i8,
                    float* __restrict__ out_f32,
                    int N, int K, int GN) {
  __shared__ __align__(16) int8_t lA[2][128 * 64];
  __shared__ __align__(16) int8_t lB[2][128 * 64];
  __shared__ float red[4];

  // bijective XCD swizzle (m204): contiguous work chunk per XCD
  const int nwg = gridDim.x;
  const int q = nwg >> 3, rr = nwg & 7;
  const int xcd = blockIdx.x & 7, sub = blockIdx.x >> 3;
  const int wg = (xcd < rr ? xcd * (q + 1) : rr * (q + 1) + (xcd - rr) * q) + sub;
  const int bx = wg % GN;   // n-tile (fastest: shares A panel)
  const int by = wg / GN;   // m-tile

  const int t = threadIdx.x;
  const int lane = t & 63;
  const int wave = t >> 6;
  const int wr = wave >> 1;
  const int wc = wave & 1;
  const size_t m0 = (size_t)by * 128;
  const int n0 = bx * 128;

  const int8_t* Ab = A + m0 * (size_t)K;
  const int8_t* Bb = B + (size_t)n0 * (size_t)K;

  v4i acc[4][4] = {};
  const int KT = K >> 6;  // BK = 64

  // Staging: linear LDS fill; XOR slot-swizzle f(row)=(row>>1)&3 pre-applied
  // on the GLOBAL source address (both-sides rule). 64B rows = 4 x 16B slots.
  // Measured 0 bank conflicts (round 4).
  const int row0 = t >> 2;
  const int ss = (t & 3) ^ ((row0 >> 1) & 3);
  const int ubase = __builtin_amdgcn_readfirstlane((t & 192) * 16);
  const size_t srcA0 = (size_t)row0 * K + (size_t)(ss * 16);
  const size_t srcA1 = (size_t)(row0 + 64) * K + (size_t)(ss * 16);

  auto stage = [&](int buf, int kt) {
    const int8_t* ga = Ab + kt * 64;
    const int8_t* gb = Bb + kt * 64;
    __builtin_amdgcn_global_load_lds(GPTR(ga + srcA0), LPTR(&lA[buf][ubase]), 16, 0, 0);
    __builtin_amdgcn_global_load_lds(GPTR(ga + srcA1), LPTR(&lA[buf][4096 + ubase]), 16, 0, 0);
    __builtin_amdgcn_global_load_lds(GPTR(gb + srcA0), LPTR(&lB[buf][ubase]), 16, 0, 0);
    __builtin_amdgcn_global_load_lds(GPTR(gb + srcA1), LPTR(&lB[buf][4096 + ubase]), 16, 0, 0);
  };

  const int r15 = lane & 15;
  const int q4 = lane >> 4;

  auto compute = [&](int buf) {
    v4i af[4], bf[4];
#pragma unroll
    for (int fr = 0; fr < 4; ++fr) {
      const int row = wr * 64 + fr * 16 + r15;
      const int slot = q4 ^ ((row >> 1) & 3);
      af[fr] = *(const v4i*)(&lA[buf][row * 64 + slot * 16]);
    }
#pragma unroll
    for (int fc = 0; fc < 4; ++fc) {
      const int row = wc * 64 + fc * 16 + r15;
      const int slot = q4 ^ ((row >> 1) & 3);
      bf[fc] = *(const v4i*)(&lB[buf][row * 64 + slot * 16]);
    }
#pragma unroll
    for (int fr = 0; fr < 4; ++fr)
#pragma unroll
      for (int fc = 0; fc < 4; ++fc)
        acc[fr][fc] = __builtin_amdgcn_mfma_i32_16x16x64_i8(af[fr], bf[fc], acc[fr][fc], 0, 0, 0);
  };

  stage(0, 0);
  asm volatile("s_waitcnt vmcnt(0)" ::: "memory");
  __syncthreads();
  int cur = 0;
  for (int kt = 1; kt < KT; ++kt) {
    stage(cur ^ 1, kt);   // issue next-tile loads BEFORE compute
    compute(cur);
    __syncthreads();      // drains vmcnt+lgkmcnt: next tile ready
    cur ^= 1;
  }
  compute(cur);

  // Epilogue. C layout (verified r1-r3): n = n0 + wc*64 + fc*16 + (lane&15),
  // m = m0 + wr*64 + fr*16 + (lane>>4)*4 + r.
  const int rb = q4 * 4;

  if constexpr (EPI == 0) {
    // max_m(acc[m][n] + b[n]) = (max_m acc[:,n]) + b[n]: int max, then 1 add.
    float lm = -3.4e38f;
#pragma unroll
    for (int fc = 0; fc < 4; ++fc) {
      int im = acc[0][fc][0];
#pragma unroll
      for (int fr = 0; fr < 4; ++fr)
#pragma unroll
        for (int r = 0; r < 4; ++r) im = max(im, acc[fr][fc][r]);
      const float bv = bias[n0 + wc * 64 + fc * 16 + r15];
      lm = fmaxf(lm, (float)im + bv);
    }
    lm = wave_max(lm);
    if (lane == 0) red[wave] = lm;
    __syncthreads();
    if (t == 0)
      partial[wg] = fmaxf(fmaxf(red[0], red[1]), fmaxf(red[2], red[3]));
  } else if constexpr (EPI == 1) {
    const float sx = __uint_as_float(scal[0]) / 127.0f;
    const float sw = __uint_as_float(scal[1]) / 127.0f;
    const float s1 = sw * sx;
    const float sh = __uint_as_float(scal[3]) / 127.0f;
    const float inv_sh = __builtin_amdgcn_rcpf(sh);
#pragma unroll
    for (int fc = 0; fc < 4; ++fc) {
      const int n = n0 + wc * 64 + fc * 16 + r15;
      const float bv = bias[n];
#pragma unroll
      for (int fr = 0; fr < 4; ++fr) {
#pragma unroll
        for (int r = 0; r < 4; ++r) {
          const size_t m = m0 + (size_t)(wr * 64 + fr * 16 + rb + r);
          const float f = ((float)acc[fr][fc][r] + bv) * s1;
          const float g = gelu_exact(f);
          const float qv = rintf(fminf(fmaxf(g * inv_sh, -128.0f), 127.0f));
          out_i8[m * (size_t)N + n] = (int8_t)(int)qv;
        }
      }
    }
  } else {
    const float sw2 = __uint_as_float(scal[2]) / 127.0f;
    const float sh = __uint_as_float(scal[3]) / 127.0f;
    const float x2max = 127.0f * sh;
    const float sx2 = x2max / 127.0f;
    const float s2 = sw2 * sx2;
#pragma unroll
    for (int fc = 0; fc < 4; ++fc) {
      const int n = n0 + wc * 64 + fc * 16 + r15;
      const float bv = bias[n];
#pragma unroll
      for (int fr = 0; fr < 4; ++fr) {
#pragma unroll
        for (int r = 0; r < 4; ++r) {
          const size_t m = m0 + (size_t)(wr * 64 + fr * 16 + rb + r);
          out_f32[m * (size_t)N + n] = ((float)acc[fr][fc][r] + bv) * s2;
        }
      }
    }
  }
}

extern "C" void kernel_launch(void* const* d_in, const int* in_sizes, int n_in,
                              void* d_out, int out_size, void* d_ws, size_t ws_size,
                              hipStream_t stream) {
  const float* x   = (const float*)d_in[0];
  const float* sxp = (const float*)d_in[1];
  const float* w1  = (const float*)d_in[2];
  const float* b1  = (const float*)d_in[3];
  const float* w2  = (const float*)d_in[4];
  const float* b2  = (const float*)d_in[5];

  const int H = in_sizes[3];      // 1536
  const int D = in_sizes[5];      // 384
  const int M = in_sizes[0] / D;  // 25216 = 197*128
  const int GM = M / 128;         // 197
  const int GN1 = H / 128;        // 12
  const int GN2 = D / 128;        // 3

  uint8_t* ws = (uint8_t*)d_ws;
  unsigned* scal = (unsigned*)ws;  // [0]=max|x2| [1]=max|w1| [2]=max|w2| [3]=max|g|
  size_t off = 256;
  float* partial = (float*)(ws + off); off += 16384;
  int8_t* qx  = (int8_t*)(ws + off); off += (size_t)M * D;
  int8_t* qw1 = (int8_t*)(ws + off); off += (size_t)H * D;
  int8_t* qw2 = (int8_t*)(ws + off); off += (size_t)D * H;
  int8_t* qh  = (int8_t*)(ws + off); off += (size_t)M * H;
  (void)ws_size; (void)n_in; (void)out_size;

  hipMemsetAsync(scal, 0, 16, stream);

  absmax3_kernel<<<dim3(768), dim3(256), 0, stream>>>(
      x, M * D / 4, sxp, w1, H * D / 4, w2, D * H / 4, scal);

  quantize3_kernel<<<dim3(2304), dim3(256), 0, stream>>>(
      x, M * D / 4, sxp, w1, H * D / 4, w2, D * H / 4, scal, qx, qw1, qw2);

  dim3 blk(256);
  dim3 g1(GN1 * GM);  // 1D grid, swizzled in-kernel
  gemm_i8_kernel<0><<<g1, blk, 0, stream>>>(qx, qw1, b1, scal, partial, nullptr, nullptr, H, D, GN1);
  reduce_scale_kernel<<<1, 256, 0, stream>>>(partial, GM * GN1, scal);
  gemm_i8_kernel<1><<<g1, blk, 0, stream>>>(qx, qw1, b1, scal, nullptr, qh, nullptr, H, D, GN1);

  dim3 g2(GN2 * GM);  // 591
  gemm_i8_kernel<2><<<g2, blk, 0, stream>>>(qh, qw2, b2, scal, nullptr, nullptr, (float*)d_out, D, H, GN2);
}